// Round 14
// baseline (188.554 us; speedup 1.0000x reference)
//
#include <hip/hip_runtime.h>
#include <hip/hip_bf16.h>

#define NTOK 512
#define TJ 32
#define NHALF 8            // j-tiles per half-block (2 blocks per i)
#define EPSF 1e-5f

typedef __attribute__((ext_vector_type(4))) float f32x4;
typedef __attribute__((ext_vector_type(8))) short bf16x8;
typedef __attribute__((ext_vector_type(4))) short bf16x4;

struct HL { short hi; short lo; };

__device__ __forceinline__ short f2bf(float x) {
  __hip_bfloat16 h = __float2bfloat16(x);
  return *reinterpret_cast<short*>(&h);
}
__device__ __forceinline__ float bf2f(short s) {
  unsigned int u = ((unsigned int)(unsigned short)s) << 16;
  return __uint_as_float(u);
}
// RNE split x ~= hi + lo (~17 mantissa bits) -- R13 showed trunc-split saves no
// time (not VALU-bound) and doubles absmax; RNE restored everywhere.
__device__ __forceinline__ HL splitbf(float x) {
  HL r;
  r.hi = f2bf(x);
  r.lo = f2bf(x - bf2f(r.hi));
  return r;
}

// Single-buffered main-loop LDS (R5's proven 57us structure; maskf removed --
// mask pre-multiplied into f0s/f1s at stage time, bitwise-exact). ~31.9 KB ->
// 2 blocks/CU: two INDEPENDENT 8-wave barrier domains per CU (the R5-vs-R10
// lesson: barrier scope is worth 18 us at fixed 16 waves/CU).
struct __align__(16) SMemMain {
  float f0s[32*17];      // [j][f] * mask[j], stride 17
  float f1s[32*49];      // [j][c*3+x] * mask[j], stride 49
  float rhs[96];         // [j*3+x] (unmasked; only multiplies masked factors)
  short rbfHL[32*40];    // [j][k]: k<16 hi, k>=16 lo; 80B row stride
  short Hh[128*40];      // [h][j] bf16 hi, stride 40
  short Hl[128*40];      // lo
};
union __align__(16) SMemU {
  SMemMain m;
  struct {               // epilogue region (disjoint lifetime, ~21 KB)
    float ACCs[128*33];
    float biasR[128];
    float part[512];
    float m00s[16], m10s[16], p01s[48], p11s[48], rawbs[48], nrms[16];
  } e;
};

// ONE kernel, 1024 blocks (i = bid>>1, j-half = bid&1), 512 threads = 8 waves.
// Main loop = R5's verbatim 57us structure (+ exact mask-premult). Merge: the
// 2nd-layer contraction is LINEAR in ACC, so each block contracts its partial
// ACC in-block to 64 floats, atomicAdds them to ws (coherent point -- no
// __threadfence/L2-writeback, R9's 380us lesson), vmcnt(0)-orders, bumps an
// arrival counter; LAST arrival atomic-reads totals and runs LN. 2
// contributions/slot -> IEEE-commutative -> deterministic. No spin, no fence.
// NEVER launch_bounds(x,8): reg wall proven R3+R11.
__global__ __launch_bounds__(512, 4) void tfn_fused(
    const float* __restrict__ f0,  const float* __restrict__ f1,
    const float* __restrict__ rbf, const float* __restrict__ rhat,
    const int*  __restrict__ mask,
    const float* __restrict__ w00a, const float* __restrict__ b00a,
    const float* __restrict__ w00b, const float* __restrict__ b00b,
    const float* __restrict__ w10a, const float* __restrict__ b10a,
    const float* __restrict__ w10b, const float* __restrict__ b10b,
    const float* __restrict__ w01a, const float* __restrict__ b01a,
    const float* __restrict__ w01b, const float* __restrict__ b01b,
    const float* __restrict__ w11a, const float* __restrict__ b11a,
    const float* __restrict__ w11b, const float* __restrict__ b11b,
    const float* __restrict__ g0, const float* __restrict__ be0,
    const float* __restrict__ g1, const float* __restrict__ be1,
    float* __restrict__ ws, int* __restrict__ cnt,
    float* __restrict__ out)
{
  __shared__ SMemU sm;
  __shared__ int lastflag;
  const int bid = blockIdx.x;
  const int i = bid >> 1;
  const int jbase = (bid & 1) * (NHALF * TJ);
  const int t = threadIdx.x;
  const int w = t >> 6;
  const int lane = t & 63;
  const int col = lane & 15;
  const int quad = lane >> 4;

  // ---- per-wave WA B-frags: bw1 = [Whi | Whi], bw2 = [Wlo | 0] ----
  bf16x8 bw1, bw2;
  float bav;
  {
    const int h = w*16 + col;
    const float* wa = (w < 2) ? (w00a + h*16) : (w < 4) ? (w10a + (h-32)*16)
                    : (w < 6) ? (w01a + (h-64)*16) : (w11a + (h-96)*16);
    bav = (w < 2) ? b00a[h] : (w < 4) ? b10a[h-32] : (w < 6) ? b01a[h-64] : b11a[h-96];
    #pragma unroll
    for (int e = 0; e < 8; ++e) {
      HL s = splitbf(wa[(quad & 1)*8 + e]);
      bw1[e] = s.hi;
      bw2[e] = (quad < 2) ? s.lo : (short)0;
    }
  }

  // ---- per-lane LHS constants (wave-uniform branch selectors) ----
  int fdiv = 0, xrem = 0, cidx = 0;
  if (w >= 2 && w < 5) { const int idx = (w-2)*16 + col; fdiv = idx/3; xrem = idx - 3*fdiv; }
  if (w >= 5) cidx = (w-5)*16 + col;
  const int hb = (w == 0) ? 0 : (w == 1) ? 2 : (w < 5) ? 4 : 6;

  const int jrow = t >> 4, jfeat = t & 15;

  // ---- prefetch tile 0 ----
  float pf_f0, pf_f1_0, pf_f1_1, pf_f1_2, pf_rh = 0.f, pf_rbf, pf_mkf;
  {
    pf_f0   = f0[(jbase + jrow)*16 + jfeat];
    { const float* fp = f1 + (size_t)(jbase + jrow)*48 + 3*jfeat;
      pf_f1_0 = fp[0]; pf_f1_1 = fp[1]; pf_f1_2 = fp[2]; }
    if (t < 96) pf_rh = rhat[((size_t)i*NTOK + jbase)*3 + t];
    pf_mkf  = mask[(size_t)i*NTOK + jbase + jrow] ? 1.f : 0.f;
    pf_rbf  = rbf[((size_t)i*NTOK + jbase + jrow)*16 + jfeat];
  }

  f32x4 acc0 = {0.f,0.f,0.f,0.f}, acc1 = {0.f,0.f,0.f,0.f};
  float biasp = 0.f;
  const f32x4 zc = {0.f,0.f,0.f,0.f};

  for (int tile = 0; tile < NHALF; ++tile) {
    // ---- stage regs -> LDS (masked) ----
    sm.m.f0s[jrow*17 + jfeat] = pf_mkf * pf_f0;
    { float* f1d = &sm.m.f1s[jrow*49 + 3*jfeat];
      f1d[0] = pf_mkf * pf_f1_0; f1d[1] = pf_mkf * pf_f1_1; f1d[2] = pf_mkf * pf_f1_2; }
    if (t < 96) sm.m.rhs[t] = pf_rh;
    { HL s = splitbf(pf_rbf);
      sm.m.rbfHL[jrow*40 + jfeat]      = s.hi;
      sm.m.rbfHL[jrow*40 + 16 + jfeat] = s.lo; }
    __syncthreads();   // staging visible

    // ---- prefetch tile+1 ----
    if (tile + 1 < NHALF) {
      const int j0 = jbase + (tile+1)*TJ;
      pf_f0   = f0[(j0 + jrow)*16 + jfeat];
      const float* fp = f1 + (size_t)(j0 + jrow)*48 + 3*jfeat;
      pf_f1_0 = fp[0]; pf_f1_1 = fp[1]; pf_f1_2 = fp[2];
      if (t < 96) pf_rh = rhat[((size_t)i*NTOK + j0)*3 + t];
      pf_mkf  = mask[(size_t)i*NTOK + j0 + jrow] ? 1.f : 0.f;
      pf_rbf  = rbf[((size_t)i*NTOK + j0 + jrow)*16 + jfeat];
    }

    // ---- phase A: H = silu(rbf @ WA^T + ba) ----
    {
      const bf16x8 a0 = *(const bf16x8*)&sm.m.rbfHL[col*40 + quad*8];
      const bf16x8 a1 = *(const bf16x8*)&sm.m.rbfHL[(16+col)*40 + quad*8];
      f32x4 d0 = __builtin_amdgcn_mfma_f32_16x16x32_bf16(a0, bw1, zc, 0, 0, 0);
      d0 = __builtin_amdgcn_mfma_f32_16x16x32_bf16(a0, bw2, d0, 0, 0, 0);
      f32x4 d1 = __builtin_amdgcn_mfma_f32_16x16x32_bf16(a1, bw1, zc, 0, 0, 0);
      d1 = __builtin_amdgcn_mfma_f32_16x16x32_bf16(a1, bw2, d1, 0, 0, 0);
      bf16x4 hv, lv;
      #pragma unroll
      for (int r = 0; r < 4; ++r) {
        float p = d0[r] + bav;
        float s = p * __builtin_amdgcn_rcpf(1.f + __expf(-p));
        HL e2 = splitbf(s); hv[r] = e2.hi; lv[r] = e2.lo;
      }
      *(bf16x4*)&sm.m.Hh[(w*16+col)*40 + quad*4] = hv;
      *(bf16x4*)&sm.m.Hl[(w*16+col)*40 + quad*4] = lv;
      #pragma unroll
      for (int r = 0; r < 4; ++r) {
        float p = d1[r] + bav;
        float s = p * __builtin_amdgcn_rcpf(1.f + __expf(-p));
        HL e2 = splitbf(s); hv[r] = e2.hi; lv[r] = e2.lo;
      }
      *(bf16x4*)&sm.m.Hh[(w*16+col)*40 + 16 + quad*4] = hv;
      *(bf16x4*)&sm.m.Hl[(w*16+col)*40 + 16 + quad*4] = lv;
    }

    // ---- LHS: per-lane phase-B A-frag (inputs pre-masked) ----
    bf16x8 afh, afl;
    {
      const int jb = quad*8;
      float v[8];
      if (w == 0) {
        #pragma unroll
        for (int jj = 0; jj < 8; ++jj) v[jj] = sm.m.f0s[(jb+jj)*17 + col];
      } else if (w < 5) {
        float rwin[24];
        #pragma unroll
        for (int q4 = 0; q4 < 6; ++q4) {
          const float4 rr = *(const float4*)&sm.m.rhs[jb*3 + q4*4];
          rwin[q4*4+0]=rr.x; rwin[q4*4+1]=rr.y; rwin[q4*4+2]=rr.z; rwin[q4*4+3]=rr.w;
        }
        if (w == 1) {
          #pragma unroll
          for (int jj = 0; jj < 8; ++jj) {
            const float* fr = &sm.m.f1s[(jb+jj)*49 + col*3];
            v[jj] = rwin[jj*3+0]*fr[0] + rwin[jj*3+1]*fr[1] + rwin[jj*3+2]*fr[2];
          }
        } else {
          #pragma unroll
          for (int jj = 0; jj < 8; ++jj)
            v[jj] = sm.m.f0s[(jb+jj)*17 + fdiv] * rwin[jj*3 + xrem];
        }
      } else {
        #pragma unroll
        for (int jj = 0; jj < 8; ++jj) v[jj] = sm.m.f1s[(jb+jj)*49 + cidx];
      }
      #pragma unroll
      for (int jj = 0; jj < 8; ++jj) {
        biasp += v[jj];
        HL s = splitbf(v[jj]);
        afh[jj] = s.hi; afl[jj] = s.lo;
      }
    }
    __syncthreads();   // H visible; staging fully consumed

    // ---- phase B: ACC += L^T * H ----
    {
      const bf16x8 b0h = *(const bf16x8*)&sm.m.Hh[(hb*16+col)*40 + quad*8];
      const bf16x8 b0l = *(const bf16x8*)&sm.m.Hl[(hb*16+col)*40 + quad*8];
      const bf16x8 b1h = *(const bf16x8*)&sm.m.Hh[((hb+1)*16+col)*40 + quad*8];
      const bf16x8 b1l = *(const bf16x8*)&sm.m.Hl[((hb+1)*16+col)*40 + quad*8];
      acc0 = __builtin_amdgcn_mfma_f32_16x16x32_bf16(afl, b0h, acc0, 0, 0, 0);
      acc0 = __builtin_amdgcn_mfma_f32_16x16x32_bf16(afh, b0l, acc0, 0, 0, 0);
      acc0 = __builtin_amdgcn_mfma_f32_16x16x32_bf16(afh, b0h, acc0, 0, 0, 0);
      acc1 = __builtin_amdgcn_mfma_f32_16x16x32_bf16(afl, b1h, acc1, 0, 0, 0);
      acc1 = __builtin_amdgcn_mfma_f32_16x16x32_bf16(afh, b1l, acc1, 0, 0, 0);
      acc1 = __builtin_amdgcn_mfma_f32_16x16x32_bf16(afh, b1h, acc1, 0, 0, 0);
    }
  }

  __syncthreads();   // main LDS dead -> epilogue region live

  // ---- dump partial ACC + wave-reduced bias to LDS ----
  #pragma unroll
  for (int r = 0; r < 4; ++r) {
    sm.e.ACCs[(w*16 + quad*4 + r)*33 + col]      = acc0[r];
    sm.e.ACCs[(w*16 + quad*4 + r)*33 + 16 + col] = acc1[r];
  }
  biasp += __shfl_xor(biasp, 16);
  biasp += __shfl_xor(biasp, 32);
  if (lane < 16) sm.e.biasR[w*16 + col] = biasp;
  __syncthreads();

  // ---- partial 2nd-layer contraction (linear in ACC), 4-way d-split ----
  {
    const int tt = t & 127, g4 = t >> 7;   // g4 0..3
    float s = 0.f;
    if (tt < 16) {
      const int o = tt;
      #pragma unroll
      for (int dd = 0; dd < 4; ++dd) {
        const int d = g4 + dd*4;
        const float* wrow = w00b + (d*16 + o)*32;
        float ss = 0.f;
        #pragma unroll
        for (int hh = 0; hh < 32; ++hh) ss += wrow[hh] * sm.e.ACCs[d*33 + hh];
        s += ss + b00b[d*16 + o] * sm.e.biasR[d];
      }
    } else if (tt < 32) {
      const int o = tt - 16;
      #pragma unroll
      for (int dd = 0; dd < 4; ++dd) {
        const int c = g4 + dd*4, m = 16 + c;
        const float* wrow = w10b + (c*16 + o)*32;
        float ss = 0.f;
        #pragma unroll
        for (int hh = 0; hh < 32; ++hh) ss += wrow[hh] * sm.e.ACCs[m*33 + hh];
        s += ss + b10b[c*16 + o] * sm.e.biasR[m];
      }
    } else if (tt < 80) {
      const int idx = tt - 32, g = idx/3, x = idx - 3*g;
      #pragma unroll
      for (int dd = 0; dd < 4; ++dd) {
        const int f = g4 + dd*4, m = 32 + f*3 + x;
        const float* wrow = w01b + (f*16 + g)*32;
        float ss = 0.f;
        #pragma unroll
        for (int hh = 0; hh < 32; ++hh) ss += wrow[hh] * sm.e.ACCs[m*33 + hh];
        s += ss + b01b[f*16 + g] * sm.e.biasR[m];
      }
    } else {
      const int idx = tt - 80, g = idx/3, x = idx - 3*g;
      #pragma unroll
      for (int dd = 0; dd < 4; ++dd) {
        const int k = g4 + dd*4, m = 80 + k*3 + x;
        const float* wrow = w11b + (k*16 + g)*32;
        float ss = 0.f;
        #pragma unroll
        for (int hh = 0; hh < 32; ++hh) ss += wrow[hh] * sm.e.ACCs[m*33 + hh];
        s += ss + b11b[k*16 + g] * sm.e.biasR[m];
      }
    }
    sm.e.part[t] = s;
  }
  __syncthreads();

  if (t < 128) {
    const float s = sm.e.part[t] + sm.e.part[t+128] + sm.e.part[t+256] + sm.e.part[t+384];
    if (t < 16) sm.e.m00s[t] = s;
    else if (t < 32) sm.e.m10s[t-16] = s;
    else if (t < 80) sm.e.p01s[t-32] = s;
    else sm.e.p11s[t-80] = s;
  }
  __syncthreads();

  // ---- merge: 64 atomicAdds (coherent, no fence), vmcnt-ordered counter ----
  float* wsi = ws + (size_t)i * 64;
  if (t < 16) {
    atomicAdd(&wsi[t], sm.e.m00s[t] + sm.e.m10s[t]);
  } else if (t < 64) {
    const int idx = t - 16;
    atomicAdd(&wsi[16 + idx], sm.e.p01s[idx] + sm.e.p11s[idx]);
  }
  asm volatile("s_waitcnt vmcnt(0)" ::: "memory");   // data atomics at coherent point
  __syncthreads();                                   // ...for ALL threads of the block
  if (t == 0) lastflag = atomicAdd(&cnt[i], 1);      // arrival order at coherent point
  __syncthreads();
  if (lastflag == 0) return;                         // first block done

  // ================= LN epilogue (last-arriving block only) =================
  // Atomic-loads (add 0.0f) return the coherent totals; peer's data atomics
  // completed before its counter atomic (vmcnt-ordered), so totals are final.
  if (t < 64) sm.e.part[t] = atomicAdd(&wsi[t], 0.f);
  __syncthreads();

  if (t < 16) {
    float vv = sm.e.part[t];
    float mu = 0.f;
    #pragma unroll
    for (int k = 0; k < 16; ++k) mu += sm.e.part[k];
    mu *= (1.f/16.f);
    float var = 0.f;
    #pragma unroll
    for (int k = 0; k < 16; ++k) { float d = sm.e.part[k] - mu; var += d*d; }
    var *= (1.f/16.f);
    out[(size_t)i*16 + t] = (vv - mu) * rsqrtf(var + EPSF) * g0[t] + be0[t];
    const float r0v = sm.e.part[16 + t*3 + 0];
    const float r1v = sm.e.part[16 + t*3 + 1];
    const float r2v = sm.e.part[16 + t*3 + 2];
    sm.e.rawbs[t*3+0] = r0v; sm.e.rawbs[t*3+1] = r1v; sm.e.rawbs[t*3+2] = r2v;
    sm.e.nrms[t] = fmaxf(sqrtf(r0v*r0v + r1v*r1v + r2v*r2v), 1e-8f);
  }
  __syncthreads();
  if (t < 16) {
    float mu = 0.f;
    #pragma unroll
    for (int k = 0; k < 16; ++k) mu += sm.e.nrms[k];
    mu *= (1.f/16.f);
    float var = 0.f;
    #pragma unroll
    for (int k = 0; k < 16; ++k) { float d = sm.e.nrms[k] - mu; var += d*d; }
    var *= (1.f/16.f);
    const float ln = (sm.e.nrms[t] - mu) * rsqrtf(var + EPSF) * g1[t] + be1[t];
    const float scale = ln / sm.e.nrms[t];
    const size_t base = (size_t)NTOK*16 + (size_t)i*48 + t*3;
    out[base+0] = sm.e.rawbs[t*3+0] * scale;
    out[base+1] = sm.e.rawbs[t*3+1] * scale;
    out[base+2] = sm.e.rawbs[t*3+2] * scale;
  }
}

extern "C" void kernel_launch(void* const* d_in, const int* in_sizes, int n_in,
                              void* d_out, int out_size, void* d_ws, size_t ws_size,
                              hipStream_t stream) {
  int idx_f0 = -1, idx_f1 = -1, idx_rbf = -1, idx_rhat = -1, idx_mask = -1;
  int wa_i[4], ba_i[4], wb_i[4], bb_i[4], g_i[4];
  int nwa = 0, nba = 0, nwb = 0, nbb = 0, ng = 0;
  for (int k = 0; k < n_in; ++k) {
    const int s = in_sizes[k];
    if      (s == 4194304) idx_rbf  = k;
    else if (s == 786432)  idx_rhat = k;
    else if (s == 262144)  idx_mask = k;
    else if (s == 24576)   idx_f1   = k;
    else if (s == 8192)    { if (idx_f0 < 0) idx_f0 = k; else if (nwb < 4) wb_i[nwb++] = k; }
    else if (s == 512)     { if (nwa < 4) wa_i[nwa++] = k; }
    else if (s == 32)      { if (nba < 4) ba_i[nba++] = k; }
    else if (s == 256)     { if (nbb < 4) bb_i[nbb++] = k; }
    else if (s == 16)      { if (ng  < 4) g_i[ng++]  = k; }
  }
  const bool ok = idx_f0 >= 0 && idx_f1 >= 0 && idx_rbf >= 0 && idx_rhat >= 0 &&
                  idx_mask >= 0 && nwa == 4 && nba == 4 && nwb == 4 && nbb == 4 && ng == 4;
  if (!ok) {
    idx_f0 = 1; idx_f1 = 2; idx_rbf = 3; idx_rhat = 4; idx_mask = 5;
    for (int q = 0; q < 4; ++q) {
      wa_i[q] = 6 + q*4; ba_i[q] = 7 + q*4; wb_i[q] = 8 + q*4; bb_i[q] = 9 + q*4;
      g_i[q] = 22 + q;
    }
  }
  float* ws = (float*)d_ws;                       // 512 * 64 floats of partial sums
  int* cnt = (int*)((char*)d_ws + 512*64*sizeof(float));   // 512 arrival counters
  hipMemsetAsync(d_ws, 0, 512*64*sizeof(float) + 512*sizeof(int), stream);
  tfn_fused<<<1024, 512, 0, stream>>>(
      (const float*)d_in[idx_f0],  (const float*)d_in[idx_f1],
      (const float*)d_in[idx_rbf], (const float*)d_in[idx_rhat],
      (const int*)d_in[idx_mask],
      (const float*)d_in[wa_i[0]], (const float*)d_in[ba_i[0]],
      (const float*)d_in[wb_i[0]], (const float*)d_in[bb_i[0]],
      (const float*)d_in[wa_i[1]], (const float*)d_in[ba_i[1]],
      (const float*)d_in[wb_i[1]], (const float*)d_in[bb_i[1]],
      (const float*)d_in[wa_i[2]], (const float*)d_in[ba_i[2]],
      (const float*)d_in[wb_i[2]], (const float*)d_in[bb_i[2]],
      (const float*)d_in[wa_i[3]], (const float*)d_in[ba_i[3]],
      (const float*)d_in[wb_i[3]], (const float*)d_in[bb_i[3]],
      (const float*)d_in[g_i[0]], (const float*)d_in[g_i[1]],
      (const float*)d_in[g_i[2]], (const float*)d_in[g_i[3]],
      ws, cnt, (float*)d_out);
}